// Round 7
// baseline (305.686 us; speedup 1.0000x reference)
//
#include <hip/hip_runtime.h>

// Problem constants
#define N_NODES 50000
#define N_EDGES 800000
#define NFEAT 512
#define NHID 256
#define NCLASS 64
#define NCOMB 576
#define NPAD 640             // NCOMB padded to 5x128 col-tiles (zero cols)
#define NSKIP 320            // NHID + NCLASS (skip0 | skip1), bf16, biases folded
#define RRELU_SLOPE 0.2291666666666667f

typedef __attribute__((ext_vector_type(8))) short bf16x8;
typedef __attribute__((ext_vector_type(4))) float f32x4;
typedef __attribute__((ext_vector_type(2))) float f32x2;

// async global->LDS, 16B per lane; dest = wave-uniform base + lane*16
#define GLOAD_LDS16(g, l)                                                      \
    __builtin_amdgcn_global_load_lds(                                          \
        (const __attribute__((address_space(1))) void*)(g),                    \
        (__attribute__((address_space(3))) void*)(l), 16, 0, 0)

__device__ __forceinline__ unsigned short f2bf(float f) {
    unsigned int x = __float_as_uint(f);
    unsigned int r = (x + 0x7fffu + ((x >> 16) & 1u)) >> 16;
    return (unsigned short)r;
}
__device__ __forceinline__ float bf2f(unsigned short u) {
    return __uint_as_float(((unsigned int)u) << 16);
}
__device__ __forceinline__ float bf_lo(unsigned int u) { return __uint_as_float(u << 16); }
__device__ __forceinline__ float bf_hi(unsigned int u) { return __uint_as_float(u & 0xffff0000u); }
// fp32 -> OCP e4m3 byte (RNE, saturating)
__device__ __forceinline__ unsigned char f2fp8(float v) {
    return (unsigned char)__builtin_amdgcn_cvt_pk_fp8_f32(v, v, 0, false);
}

// ---------------- prep: pack blocks + grid-stride stream cast ---------------
// Ledger r3-r6 says the old one-shot branchy prep ran at only ~3.8 TB/s
// (~40 us). Split: blocks [0,PK_BLK) pack Bt+bias (tiny, branchy, done fast);
// blocks [PK_BLK, PK_BLK+XC_BLK) run a branch-free grid-stride float4 cast.
#define P_BT 327680          // 640*512 Bt pack items
#define P_TOT 328320         // + 640 bias
#define PK_BLK 1283          // ceil(328320/256)
#define XC_BLK 2048
#define XC_N 6400000         // x cast: float4 items (50000*512/4)

__global__ __launch_bounds__(256)
void prep(const float* __restrict__ x, const float* __restrict__ w1,
          const float* __restrict__ w2, const float* __restrict__ w4,
          const float* __restrict__ b1, const float* __restrict__ b2,
          const float* __restrict__ b3, const float* __restrict__ b4,
          unsigned short* __restrict__ xb, unsigned short* __restrict__ Bt,
          float* __restrict__ biasb) {
    int b = blockIdx.x;
    if (b < PK_BLK) {
        int i = b * 256 + threadIdx.x;
        if (i < P_BT) {
            int c = i >> 9;            // 0..639
            int k = i & 511;
            float v = 0.f;
            if (c < NHID)            v = w1[k * NHID + c];
            else if (c < 2 * NHID)   v = w2[k * NHID + (c - NHID)];
            else if (c < NCOMB)      v = w4[k * NCLASS + (c - 2 * NHID)];
            Bt[i] = f2bf(v);
        } else if (i < P_TOT) {
            int bb = i - P_BT;         // 0..639
            float v = 0.f;
            if (bb >= NHID && bb < 2 * NHID)       v = b1[bb - NHID] + b2[bb - NHID];
            else if (bb >= 2 * NHID && bb < NCOMB) v = b3[bb - 2 * NHID] + b4[bb - 2 * NHID];
            biasb[bb] = v;
        }
        return;
    }
    // branch-free streaming cast, 2048 blocks grid-stride
    for (int i = (b - PK_BLK) * 256 + threadIdx.x; i < XC_N; i += XC_BLK * 256) {
        float4 v = ((const float4*)x)[i];
        ushort4 o;
        o.x = f2bf(v.x); o.y = f2bf(v.y); o.z = f2bf(v.z); o.w = f2bf(v.w);
        ((ushort4*)xb)[i] = o;
    }
}

// ---------------- bf16 MFMA GEMM, BK=32 double-buffered ----------------
// Tile 128 x BN, BK=32, LDS double-buffered at the SAME 32 KB footprint as
// the r0 single-buffer (r2 lesson: dbuf at 64 KB kills TLP; this keeps
// 5 blocks/CU). Per K-step: issue stage(t+1, buf^1) (fire-and-forget
// gload_lds) BEFORE compute(t), ONE barrier per step -> the barrier's
// vmcnt(0) drain only pays latency not covered by the 16-MFMA cluster.
// Swizzle (4x16B slots/row): LDS slot s of row r holds global k-octet
// s ^ ((r>>1)&3); applied pre-swizzled on the global source, inverted on
// the fragment read (both-sides rule). Full-wave b128 read = 64 distinct
// slots tiling exactly 8 bank-stripes -> conflict-free.
// MODE 0 (BN=128): XCD-co-schedule swizzle; cols<256 -> xw1 fp8;
//   256<=col<576 -> skipb bf16 (+bias). Tail blocks run prep2.
// MODE 1 (BN=64): 2D grid; fp8 out. LDS 24 KB.
#define GBM 128
#define GBK 32
#define NCB0 5               // NPAD / 128 col-blocks in mode 0
#define NRP0 392             // row-panels in mode 0, padded to multiple of 8
// prep2 tail item ranges
#define T0 800000            // ep pack
#define T1 850001            // + rowptr (50001)
#define T2 866385            // + w3t (16384)
#define T3 944209            // + weight copy, float4 items (77824)
#define TAIL_BLOCKS ((T3 + 255) / 256)

template <int BN, int MODE>
__global__ __launch_bounds__(256, 4)
void gemm_bf16(const unsigned short* __restrict__ A,   // [M,K] bf16 row-major
               const unsigned short* __restrict__ Bt,  // [*,K] bf16 row-major (B^T)
               const float* __restrict__ bias,
               unsigned char* __restrict__ C8,         // fp8 dest (mode0: xw1, mode1: hw3)
               unsigned short* __restrict__ skipb,     // mode 0 only
               int M, int K, int NC,
               const int* __restrict__ erow, const int* __restrict__ ecol,
               const float* __restrict__ ev, const float* __restrict__ w1f,
               const float* __restrict__ w2f, const float* __restrict__ w3f,
               const float* __restrict__ w4f, uint2* __restrict__ ep,
               int* __restrict__ rp, unsigned short* __restrict__ w3t,
               float* __restrict__ outw) {
    constexpr int CF = BN / 32;               // col-frags per wave (4 or 2)
    __shared__ unsigned short As[2 * GBM * GBK];  // 2 x 8 KB
    __shared__ unsigned short Bs[2 * BN * GBK];   // 2 x 8 KB (128) / 4 KB (64)
    int row0, col0;
    if (MODE == 0) {
        int b = blockIdx.x;
        if (b >= NRP0 * NCB0) {
            // ---- prep2 tail: pure memory work, overlapped with GEMM blocks
            int i = (b - NRP0 * NCB0) * 256 + threadIdx.x;
            if (i < T0) {
                uint2 e;
                e.x = (unsigned)ecol[i];
                e.y = __float_as_uint(ev[i]);
                ep[i] = e;
            } else if (i < T1) {
                int n = i - T0;            // 0..50000
                int lo = 0, hi = N_EDGES;
                while (lo < hi) {
                    int mid = (lo + hi) >> 1;
                    if (erow[mid] < n) lo = mid + 1; else hi = mid;
                }
                rp[n] = lo;
            } else if (i < T2) {
                int j = i - T1;
                int c = j >> 8;            // NHID=256
                int k = j & 255;
                w3t[j] = f2bf(w3f[k * NCLASS + c]);
            } else if (i < T3) {
                int j = i - T2;            // 0..77823
                float4* o4 = (float4*)outw;
                if (j < 32768)        o4[800000 + j] = ((const float4*)w1f)[j];
                else if (j < 65536)   o4[832768 + (j - 32768)] = ((const float4*)w2f)[j - 32768];
                else if (j < 69632)   o4[865536 + (j - 65536)] = ((const float4*)w3f)[j - 65536];
                else                  o4[869632 + (j - 69632)] = ((const float4*)w4f)[j - 69632];
            }
            return;
        }
        int g = b / (8 * NCB0);
        int w = b % (8 * NCB0);
        int r = g * 8 + (w & 7);
        int c = w >> 3;
        if (r * GBM >= M) return;           // padded tail
        row0 = r * GBM;
        col0 = c * BN;
    } else {
        col0 = blockIdx.x * BN;
        row0 = blockIdx.y * GBM;
    }
    const int tid  = threadIdx.x;
    const int lane = tid & 63;
    const int wave = tid >> 6;
    const int wr = (wave >> 1) * 64;
    const int wc = (wave & 1) * (BN / 2);
    const int lm = lane & 15;
    const int l4 = lane >> 4;       // 0..3 (k-octet within 32-k chunk)
    const int kb = (lm >> 1) & 3;   // fragment-read swizzle key = (row>>1)&3

    // staging decomposition: 1 KB per wave-issue = 16 rows x 4 16B-slots
    const int sub16 = lane >> 2;    // row within 16-row chunk
    const int gs4   = (lane & 3) ^ ((sub16 >> 1) & 3);  // pre-swizzled octet

    f32x4 acc[4][CF] = {};

    auto stage = [&](int k0, int bf) {
        #pragma unroll
        for (int p = 0; p < 2; ++p) {
            int c = wave * 2 + p;                 // 0..7 (16-row chunks)
            int gr = row0 + c * 16 + sub16;
            if (gr > M - 1) gr = M - 1;           // clamp (dups feed unsaved acc)
            GLOAD_LDS16(A + (size_t)gr * K + k0 + gs4 * 8,
                        As + bf * (GBM * GBK) + c * 512);
        }
        #pragma unroll
        for (int p = 0; p < BN / 64; ++p) {
            int c = wave * (BN / 64) + p;         // 16-row chunks of Bt
            int rb = col0 + c * 16 + sub16;
            GLOAD_LDS16(Bt + (size_t)rb * K + k0 + gs4 * 8,
                        Bs + bf * (BN * GBK) + c * 512);
        }
    };

    stage(0, 0);
    __syncthreads();

    const int nt = K / GBK;
    int cur = 0;
    for (int t = 0; t < nt; ++t) {
        if (t + 1 < nt) stage((t + 1) * GBK, cur ^ 1);   // fire-and-forget

        const unsigned short* Ab = As + cur * (GBM * GBK);
        const unsigned short* Bb = Bs + cur * (BN * GBK);
        bf16x8 bfr[CF];
        #pragma unroll
        for (int j = 0; j < CF; ++j)
            bfr[j] = *(const bf16x8*)(Bb + (wc + j * 16 + lm) * 32 + ((l4 ^ kb) * 8));
        #pragma unroll
        for (int i = 0; i < 4; ++i) {
            bf16x8 af = *(const bf16x8*)(Ab + (wr + i * 16 + lm) * 32 + ((l4 ^ kb) * 8));
            #pragma unroll
            for (int j = 0; j < CF; ++j)
                acc[i][j] = __builtin_amdgcn_mfma_f32_16x16x32_bf16(af, bfr[j], acc[i][j], 0, 0, 0);
        }

        __syncthreads();     // one barrier/step; drains next-tile loads too
        cur ^= 1;
    }

    // epilogue: C/D layout col=lane&15, row=(lane>>4)*4+reg
    #pragma unroll
    for (int i = 0; i < 4; ++i) {
        #pragma unroll
        for (int j = 0; j < CF; ++j) {
            int col = col0 + wc + j * 16 + lm;
            float bvv = (MODE == 0) ? bias[col] : 0.f;   // bias alloc'd NPAD, safe
            #pragma unroll
            for (int r = 0; r < 4; ++r) {
                int row = row0 + wr + i * 16 + l4 * 4 + r;
                if (row < M) {
                    float v = acc[i][j][r];
                    if (MODE == 0) {
                        if (col < NHID)       C8[(size_t)row * NHID + col] = f2fp8(v);
                        else if (col < NCOMB) skipb[(size_t)row * NSKIP + (col - NHID)] = f2bf(v + bvv);
                    } else {
                        C8[(size_t)row * NC + col] = f2fp8(v);
                    }
                }
            }
        }
    }
}

// ---------------- SpMM1 + skip0(+b1+b2) + RReLU -> hb (bf16) ----------------
// TWO nodes per wave (half-wave per node, 32 lanes x 8 fp8 feats via uint2
// gathers); 8 gather instrs serve 16 edge-gathers. PREDICATED 8-edge batches.
__global__ __launch_bounds__(256)
void spmm1_rrelu(const int* __restrict__ rp, const uint2* __restrict__ ep,
                 const unsigned char* __restrict__ xw1q,
                 const unsigned short* __restrict__ skipb,
                 unsigned short* __restrict__ hb, int n_nodes) {
    int n = blockIdx.x * 8 + (threadIdx.x >> 5);
    if (n >= n_nodes) return;
    int l = threadIdx.x & 31;
    int f = l * 8;             // feature base (8 fp8 per lane)
    int lo = rp[n], hi = rp[n + 1];
    float s0 = 0.f, s1 = 0.f, s2 = 0.f, s3 = 0.f;
    float s4 = 0.f, s5 = 0.f, s6 = 0.f, s7 = 0.f;
    for (int e = lo; e < hi; e += 8) {
        uint2 ed[8];
        uint2 p[8];
        #pragma unroll
        for (int q = 0; q < 8; ++q) {
            int idx = (e + q < hi) ? e + q : hi - 1;   // hi>lo guaranteed here
            ed[q] = ep[idx];
        }
        #pragma unroll
        for (int q = 0; q < 8; ++q)
            p[q] = *(const uint2*)(xw1q + (size_t)ed[q].x * NHID + f);
        #pragma unroll
        for (int q = 0; q < 8; ++q) {
            float v = (e + q < hi) ? __uint_as_float(ed[q].y) : 0.f;
            f32x2 ab = __builtin_amdgcn_cvt_pk_f32_fp8((int)p[q].x, false);
            f32x2 cd = __builtin_amdgcn_cvt_pk_f32_fp8((int)p[q].x, true);
            f32x2 ef = __builtin_amdgcn_cvt_pk_f32_fp8((int)p[q].y, false);
            f32x2 gh = __builtin_amdgcn_cvt_pk_f32_fp8((int)p[q].y, true);
            s0 += v * ab.x; s1 += v * ab.y;
            s2 += v * cd.x; s3 += v * cd.y;
            s4 += v * ef.x; s5 += v * ef.y;
            s6 += v * gh.x; s7 += v * gh.y;
        }
    }
    uint4 sk = *(const uint4*)(skipb + (size_t)n * NSKIP + f);
    float v0 = s0 + bf_lo(sk.x), v1 = s1 + bf_hi(sk.x);
    float v2 = s2 + bf_lo(sk.y), v3 = s3 + bf_hi(sk.y);
    float v4 = s4 + bf_lo(sk.z), v5 = s5 + bf_hi(sk.z);
    float v6 = s6 + bf_lo(sk.w), v7 = s7 + bf_hi(sk.w);
    v0 = (v0 >= 0.f) ? v0 : v0 * RRELU_SLOPE;
    v1 = (v1 >= 0.f) ? v1 : v1 * RRELU_SLOPE;
    v2 = (v2 >= 0.f) ? v2 : v2 * RRELU_SLOPE;
    v3 = (v3 >= 0.f) ? v3 : v3 * RRELU_SLOPE;
    v4 = (v4 >= 0.f) ? v4 : v4 * RRELU_SLOPE;
    v5 = (v5 >= 0.f) ? v5 : v5 * RRELU_SLOPE;
    v6 = (v6 >= 0.f) ? v6 : v6 * RRELU_SLOPE;
    v7 = (v7 >= 0.f) ? v7 : v7 * RRELU_SLOPE;
    uint4 o;
    o.x = (unsigned)f2bf(v0) | ((unsigned)f2bf(v1) << 16);
    o.y = (unsigned)f2bf(v2) | ((unsigned)f2bf(v3) << 16);
    o.z = (unsigned)f2bf(v4) | ((unsigned)f2bf(v5) << 16);
    o.w = (unsigned)f2bf(v6) | ((unsigned)f2bf(v7) << 16);
    *(uint4*)(hb + (size_t)n * NHID + f) = o;
}

// ---------------- SpMM2 + skip1(+b3+b4) -> out ----------------
// TWO nodes per wave (half-wave per node); 8 lanes x uint2(8 fp8) per edge,
// 4 edge slots x 2-deep = 8 edges in flight per node; shfl_xor(8,16) merge
// (stays within each 32-lane half). 4 VMEM instrs per 16 edge-gathers.
__global__ __launch_bounds__(256)
void spmm2_out(const int* __restrict__ rp, const uint2* __restrict__ ep,
               const unsigned char* __restrict__ hw3q,
               const unsigned short* __restrict__ skipb,
               float* __restrict__ out, int n_nodes) {
    int n = blockIdx.x * 8 + (threadIdx.x >> 5);
    if (n >= n_nodes) return;
    int l = threadIdx.x & 31;
    int oct = l >> 3;          // edge slot 0..3
    int f = (l & 7) * 8;       // feature base (8 fp8 per lane)
    int lo = rp[n], hi = rp[n + 1];
    float s0 = 0.f, s1 = 0.f, s2 = 0.f, s3 = 0.f;
    float s4 = 0.f, s5 = 0.f, s6 = 0.f, s7 = 0.f;
    for (int e = lo + oct; e < hi; e += 8) {
        int i1 = (e + 4 < hi) ? e + 4 : hi - 1;
        uint2 ea = ep[e], eb = ep[i1];
        uint2 pa = *(const uint2*)(hw3q + (size_t)ea.x * NCLASS + f);
        uint2 pb = *(const uint2*)(hw3q + (size_t)eb.x * NCLASS + f);
        float va = __uint_as_float(ea.y);
        float vb = (e + 4 < hi) ? __uint_as_float(eb.y) : 0.f;
        f32x2 a0 = __builtin_amdgcn_cvt_pk_f32_fp8((int)pa.x, false);
        f32x2 a1 = __builtin_amdgcn_cvt_pk_f32_fp8((int)pa.x, true);
        f32x2 a2 = __builtin_amdgcn_cvt_pk_f32_fp8((int)pa.y, false);
        f32x2 a3 = __builtin_amdgcn_cvt_pk_f32_fp8((int)pa.y, true);
        f32x2 b0 = __builtin_amdgcn_cvt_pk_f32_fp8((int)pb.x, false);
        f32x2 b1 = __builtin_amdgcn_cvt_pk_f32_fp8((int)pb.x, true);
        f32x2 b2 = __builtin_amdgcn_cvt_pk_f32_fp8((int)pb.y, false);
        f32x2 b3 = __builtin_amdgcn_cvt_pk_f32_fp8((int)pb.y, true);
        s0 += va * a0.x + vb * b0.x;
        s1 += va * a0.y + vb * b0.y;
        s2 += va * a1.x + vb * b1.x;
        s3 += va * a1.y + vb * b1.y;
        s4 += va * a2.x + vb * b2.x;
        s5 += va * a2.y + vb * b2.y;
        s6 += va * a3.x + vb * b3.x;
        s7 += va * a3.y + vb * b3.y;
    }
    s0 += __shfl_xor(s0, 8); s0 += __shfl_xor(s0, 16);
    s1 += __shfl_xor(s1, 8); s1 += __shfl_xor(s1, 16);
    s2 += __shfl_xor(s2, 8); s2 += __shfl_xor(s2, 16);
    s3 += __shfl_xor(s3, 8); s3 += __shfl_xor(s3, 16);
    s4 += __shfl_xor(s4, 8); s4 += __shfl_xor(s4, 16);
    s5 += __shfl_xor(s5, 8); s5 += __shfl_xor(s5, 16);
    s6 += __shfl_xor(s6, 8); s6 += __shfl_xor(s6, 16);
    s7 += __shfl_xor(s7, 8); s7 += __shfl_xor(s7, 16);
    if (oct == 0) {
        uint4 sv = *(const uint4*)(skipb + (size_t)n * NSKIP + NHID + f);
        float4 o1, o2;
        o1.x = s0 + bf_lo(sv.x); o1.y = s1 + bf_hi(sv.x);
        o1.z = s2 + bf_lo(sv.y); o1.w = s3 + bf_hi(sv.y);
        o2.x = s4 + bf_lo(sv.z); o2.y = s5 + bf_hi(sv.z);
        o2.z = s6 + bf_lo(sv.w); o2.w = s7 + bf_hi(sv.w);
        float4* op = (float4*)(out + (size_t)n * NCLASS + f);
        op[0] = o1;
        op[1] = o2;
    }
}

extern "C" void kernel_launch(void* const* d_in, const int* in_sizes, int n_in,
                              void* d_out, int out_size, void* d_ws, size_t ws_size,
                              hipStream_t stream) {
    const float* x    = (const float*)d_in[0];
    const int*   erow = (const int*)d_in[1];
    const int*   ecol = (const int*)d_in[2];
    const float* ev   = (const float*)d_in[3];
    const float* w1   = (const float*)d_in[4];
    const float* b1   = (const float*)d_in[5];
    const float* w2   = (const float*)d_in[6];
    const float* b2   = (const float*)d_in[7];
    const float* w3   = (const float*)d_in[8];
    const float* b3   = (const float*)d_in[9];
    const float* w4   = (const float*)d_in[10];
    const float* b4   = (const float*)d_in[11];
    float* out = (float*)d_out;

    char* ws = (char*)d_ws;
    size_t off = 0;
    auto alloc = [&](size_t bytes) -> void* {
        off = (off + 255) & ~(size_t)255;
        void* p = ws + off;
        off += bytes;
        return p;
    };

    unsigned short* xb    = (unsigned short*)alloc((size_t)N_NODES * NFEAT * 2);
    unsigned short* Bt    = (unsigned short*)alloc((size_t)NFEAT * NPAD * 2);
    float*          biasb = (float*)alloc(NPAD * 4);
    unsigned char*  xw1q  = (unsigned char*)alloc((size_t)N_NODES * NHID);
    unsigned short* skipb = (unsigned short*)alloc((size_t)N_NODES * NSKIP * 2);
    unsigned short* hb    = (unsigned short*)alloc((size_t)N_NODES * NHID * 2);
    unsigned short* w3t   = (unsigned short*)alloc((size_t)NHID * NCLASS * 2);
    unsigned char*  hw3q  = (unsigned char*)alloc((size_t)N_NODES * NCLASS);
    int*            rp    = (int*)alloc((size_t)(N_NODES + 1) * 4);
    uint2*          ep    = (uint2*)alloc((size_t)N_EDGES * 8);

    // 1) prep: pack blocks + grid-stride x-cast (target BW floor ~26 us)
    prep<<<PK_BLK + XC_BLK, 256, 0, stream>>>(x, w1, w2, w4, b1, b2, b3, b4,
                                              xb, Bt, biasb);

    // 2) fused GEMM (BK=32 dbuf): xb @ [w1|w2|w4|pad] -> xw1q (fp8) | skipb
    //    + prep2 tail blocks (ep pack, rowptr, w3t, weight copies) overlapped
    gemm_bf16<128, 0><<<NRP0 * NCB0 + TAIL_BLOCKS, 256, 0, stream>>>(
        xb, Bt, biasb, xw1q, skipb, N_NODES, NFEAT, NPAD,
        erow, ecol, ev, w1, w2, w3, w4, ep, rp, w3t, out);

    // 3) spmm(xw1) + skip0 -> rrelu -> hb (bf16); 2 nodes/wave
    spmm1_rrelu<<<(N_NODES + 7) / 8, 256, 0, stream>>>(rp, ep, xw1q, skipb, hb, N_NODES);

    // 4) hw3q = hb @ w3 (fp8 out), BK=32 dbuf
    dim3 g2(NCLASS / 64, (N_NODES + GBM - 1) / GBM);
    gemm_bf16<64, 1><<<g2, 256, 0, stream>>>(hb, w3t, nullptr, hw3q, nullptr,
                                             N_NODES, NHID, NCLASS,
                                             nullptr, nullptr, nullptr, nullptr,
                                             nullptr, nullptr, nullptr, nullptr,
                                             nullptr, nullptr, nullptr);

    // 5) out = spmm(hw3) + skip1; 2 nodes/wave
    spmm2_out<<<(N_NODES + 7) / 8, 256, 0, stream>>>(rp, ep, hw3q, skipb, out, N_NODES);
}